// Round 3
// baseline (230.293 us; speedup 1.0000x reference)
//
#include <hip/hip_runtime.h>

// Problem constants (fixed by setup_inputs)
constexpr int kC     = 21;
constexpr int kHW    = 512 * 512;        // 262144
constexpr int kB     = 8;
constexpr int kN     = kB * kHW;         // 2,097,152 pixels
constexpr int kQuads = kN / 4;           // 524,288 float4-groups
constexpr int kBlock = 256;
constexpr int kGrid  = kQuads / kBlock;  // 2048 blocks

// Native clang vector types — __builtin_nontemporal_load requires these.
typedef float fvec4 __attribute__((ext_vector_type(4)));
typedef int   ivec4 __attribute__((ext_vector_type(4)));

// R2 = R1 resubmitted verbatim (R1 bench died on infrastructure, not the
// kernel — no counters were produced; changing the kernel blind would
// confound the infra failure with the restructure under test).
//
// R1 restructure: ONLINE softmax in 7 chunks of 3 channels, manually
// double-buffered (chunk k+1 loads issued before chunk k compute).
// Rationale: the previous all-21-channels-in-registers version needed
// ~84 VGPRs for data alone (est. 110-160 total -> 2-4 waves/SIMD) and had
// a burst-then-idle memory pattern (one vmcnt(0), then ~1.5K cycles of
// pure VALU with nothing in flight). Measured ~105us = 1.7 TB/s, 27% of
// achievable. Online state is ~50 VGPRs; forcing 64 VGPRs gives
// 8 waves/SIMD and loads stay in flight for the whole kernel lifetime.
// Numerics: __expf(0)=1 exactly, so S*exp(M-nm) is a no-op whenever the
// running max doesn't move -> results track the 2-pass version closely.
__global__ __launch_bounds__(kBlock, 8) void fl_main(const float* __restrict__ x,
                                                     const int* __restrict__ tgt,
                                                     float* __restrict__ part) {
    const int gid = blockIdx.x * kBlock + threadIdx.x;   // quad index
    const int b   = gid >> 16;                           // gid / 65536
    const int hw4 = gid & 0xFFFF;

    const float* xb = x + (size_t)b * ((size_t)kC * kHW) + (size_t)hw4 * 4;

    ivec4 t4 = __builtin_nontemporal_load(
        reinterpret_cast<const ivec4*>(tgt + (size_t)gid * 4));
#pragma unroll
    for (int p = 0; p < 4; ++p) t4[p] = (t4[p] == 255) ? 0 : t4[p];  // remap

    auto LD = [&](int c) -> fvec4 {
        return __builtin_nontemporal_load(
            reinterpret_cast<const fvec4*>(xb + (size_t)c * kHW));
    };

    fvec4 M, S, XT;                 // online softmax state, 4 pixels each
    fvec4 A0, A1, A2, B0, B1, B2;   // double-buffered channel chunks

    A0 = LD(0); A1 = LD(1); A2 = LD(2);
    B0 = LD(3); B1 = LD(4); B2 = LD(5);

    // INIT from chunk {0,1,2}
#pragma unroll
    for (int p = 0; p < 4; ++p) {
        const float m = fmaxf(fmaxf(A0[p], A1[p]), A2[p]);
        M[p] = m;
        S[p] = __expf(A0[p] - m) + __expf(A1[p] - m) + __expf(A2[p] - m);
        float xt = A0[p];                      // covers t==0
        xt = (t4[p] == 1) ? A1[p] : xt;
        xt = (t4[p] == 2) ? A2[p] : xt;
        XT[p] = xt;
    }
    A0 = LD(6); A1 = LD(7); A2 = LD(8);

#define FL_STEP(V0, V1, V2, CB)                                          \
    _Pragma("unroll")                                                    \
    for (int p = 0; p < 4; ++p) {                                        \
        const float cm = fmaxf(fmaxf(V0[p], V1[p]), V2[p]);              \
        const float nm = fmaxf(M[p], cm);                                \
        float s = S[p] * __expf(M[p] - nm);                              \
        s += __expf(V0[p] - nm);                                         \
        s += __expf(V1[p] - nm);                                         \
        s += __expf(V2[p] - nm);                                         \
        S[p] = s; M[p] = nm;                                             \
        float xt = XT[p];                                                \
        xt = (t4[p] == (CB) + 0) ? V0[p] : xt;                           \
        xt = (t4[p] == (CB) + 1) ? V1[p] : xt;                           \
        xt = (t4[p] == (CB) + 2) ? V2[p] : xt;                           \
        XT[p] = xt;                                                      \
    }

    FL_STEP(B0, B1, B2, 3);   B0 = LD(9);  B1 = LD(10); B2 = LD(11);
    FL_STEP(A0, A1, A2, 6);   A0 = LD(12); A1 = LD(13); A2 = LD(14);
    FL_STEP(B0, B1, B2, 9);   B0 = LD(15); B1 = LD(16); B2 = LD(17);
    FL_STEP(A0, A1, A2, 12);  A0 = LD(18); A1 = LD(19); A2 = LD(20);
    FL_STEP(B0, B1, B2, 15);
    FL_STEP(A0, A1, A2, 18);
#undef FL_STEP

    float loss = 0.f;
#pragma unroll
    for (int p = 0; p < 4; ++p) {
        const float logpt = XT[p] - M[p] - __logf(S[p]);
        const float pt    = __expf(logpt);
        const float om    = 1.f - pt;
        loss += om * om * (-logpt);
    }
    loss *= (1.0f / (float)kN);   // prescale so the partial sum IS the mean

    // wave(64) shuffle reduction
#pragma unroll
    for (int off = 32; off > 0; off >>= 1)
        loss += __shfl_down(loss, off, 64);

    __shared__ float ws[kBlock / 64];
    const int lane = threadIdx.x & 63;
    const int wid  = threadIdx.x >> 6;
    if (lane == 0) ws[wid] = loss;
    __syncthreads();
    if (threadIdx.x == 0)
        part[blockIdx.x] = ws[0] + ws[1] + ws[2] + ws[3];   // contention-free
}

// 1 block x 256 threads: sum the 2048 partials; plain store overwrites the
// 0xAA poison, so no memset dispatch is needed.
__global__ __launch_bounds__(kBlock) void fl_reduce(const float* __restrict__ part,
                                                    float* __restrict__ out) {
    const int t = threadIdx.x;
    const fvec4 a = *reinterpret_cast<const fvec4*>(part + (size_t)t * 8);
    const fvec4 b = *reinterpret_cast<const fvec4*>(part + (size_t)t * 8 + 4);
    float s = (a[0] + a[1] + a[2] + a[3]) + (b[0] + b[1] + b[2] + b[3]);

#pragma unroll
    for (int off = 32; off > 0; off >>= 1)
        s += __shfl_down(s, off, 64);

    __shared__ float ws[kBlock / 64];
    const int lane = t & 63;
    const int wid  = t >> 6;
    if (lane == 0) ws[wid] = s;
    __syncthreads();
    if (t == 0) out[0] = ws[0] + ws[1] + ws[2] + ws[3];
}

extern "C" void kernel_launch(void* const* d_in, const int* in_sizes, int n_in,
                              void* d_out, int out_size, void* d_ws, size_t ws_size,
                              hipStream_t stream) {
    const float* x    = (const float*)d_in[0];
    const int*   tgt  = (const int*)d_in[1];
    float*       out  = (float*)d_out;
    float*       part = (float*)d_ws;    // 2048 floats = 8 KB of workspace

    fl_main<<<kGrid, kBlock, 0, stream>>>(x, tgt, part);
    fl_reduce<<<1, kBlock, 0, stream>>>(part, out);
}